// Round 15
// baseline (321.265 us; speedup 1.0000x reference)
//
#include <hip/hip_runtime.h>
#include <hip/hip_bf16.h>
#include <math.h>

// B=256 graphs, N=256 nodes/graph, DEG=8, D=128, L=3.
#define DD     128
#define NGRAPH 256
#define ECAPG  2048
#define ETOT   (NGRAPH*ECAPG)
#define NMAX   65536

typedef __attribute__((ext_vector_type(8))) short bf16x8;
typedef __attribute__((ext_vector_type(4))) float f32x4;

__device__ inline unsigned short rne_bf16(float x){
  union { float f; unsigned u; } c; c.f = x;
  unsigned u = c.u;
  return (unsigned short)((u + 0x7FFFu + ((u>>16)&1u)) >> 16);
}
__device__ inline float bf16f(unsigned short h){
  union { unsigned u; float f; } c; c.u = ((unsigned)h)<<16; return c.f;
}

// 16B global -> LDS direct (wave-uniform LDS base + lane*16)
__device__ inline void gload_lds16(const void* g, void* l){
  __builtin_amdgcn_global_load_lds(
      (const __attribute__((address_space(1))) unsigned*)g,
      (__attribute__((address_space(3))) unsigned*)l, 16, 0, 0);
}

// ---- pool_w inverse norms ----
__global__ __launch_bounds__(128) void k_wnorm(const float* pw, float* wni){
  int l = blockIdx.x, t = threadIdx.x;
  __shared__ float s[128];
  float v = pw[l*DD + t];
  s[t] = v*v; __syncthreads();
  for (int o=64;o>0;o>>=1){ if (t<o) s[t]+=s[t+o]; __syncthreads(); }
  if (t==0) wni[l] = 1.0f/sqrtf(s[0]);
}

// ---- weight prep: transpose + split to bf16 hi/lo; 15 matrices [128x128] ----
__global__ __launch_bounds__(128) void k_wprep(const float* Wq, const float* Wk, const float* Wv,
                                               const float* Ws, const float* Wt,
                                               unsigned short* whi, unsigned short* wlo){
  int b = blockIdx.x;            // w*128 + krow
  int w = b>>7, krow = b&127, n = threadIdx.x;
  int layer = w/5, which = w - layer*5;
  const float* W = (which==0)?Wq:(which==1)?Wk:(which==2)?Wv:(which==3)?Ws:Wt;
  float v = W[(size_t)layer*DD*DD + krow*DD + n];
  unsigned short h = rne_bf16(v);
  unsigned short l = rne_bf16(v - bf16f(h));
  whi[(size_t)w*DD*DD + (size_t)n*DD + krow] = h;   // transposed: [n][k]
  wlo[(size_t)w*DD*DD + (size_t)n*DD + krow] = l;
}

// ---- X split: fp32 -> bf16 hi/lo (initial x0 only) ----
__global__ __launch_bounds__(256) void k_xsplit(const float* __restrict__ X,
                                                unsigned short* __restrict__ xh,
                                                unsigned short* __restrict__ xl, int total4){
  int i = blockIdx.x*256 + threadIdx.x;
  if (i >= total4) return;
  float4 v = ((const float4*)X)[i];
  unsigned short h0=rne_bf16(v.x), h1=rne_bf16(v.y), h2=rne_bf16(v.z), h3=rne_bf16(v.w);
  unsigned short l0=rne_bf16(v.x-bf16f(h0)), l1=rne_bf16(v.y-bf16f(h1)),
                 l2=rne_bf16(v.z-bf16f(h2)), l3=rne_bf16(v.w-bf16f(h3));
  uint2 uh, ul;
  uh.x = (unsigned)h0 | ((unsigned)h1<<16); uh.y = (unsigned)h2 | ((unsigned)h3<<16);
  ul.x = (unsigned)l0 | ((unsigned)l1<<16); ul.y = (unsigned)l2 | ((unsigned)l3<<16);
  ((uint2*)xh)[i] = uh; ((uint2*)xl)[i] = ul;
}

// ---- CSR build (layer 0): deterministic chunked counting-sort scatter ----
// Also emits a degree-sorted node permutation (stable by node id) for attn
// wave pairing; pure processing-order change, zero semantic effect.
__global__ __launch_bounds__(256) void k_csr(const int* __restrict__ src, const int* __restrict__ dst,
                                             int n, int* row_start, int* row_end, int* ssrc,
                                             int* perm){
  int g = blockIdx.x, t = threadIdx.x;
  const int E = ECAPG;
  int base = g*ECAPG;
  __shared__ int lsrc[ECAPG];
  __shared__ unsigned char ldst8[ECAPG];
  __shared__ unsigned char slotc[ECAPG];
  __shared__ unsigned short off[64][256];   // 32KB
  __shared__ int sc[256];
  __shared__ int rstart[256];
  __shared__ unsigned short degv[256];
  for (int i=t; i<64*256/2; i+=256) ((unsigned*)off)[i] = 0;
  for (int i=t; i<E; i+=256){ lsrc[i]=src[base+i]; ldst8[i]=(unsigned char)(dst[base+i]-g*n); }
  __syncthreads();
  if (t < 64){
    int e0=t*32;
    for (int i=e0;i<e0+32;i++){ int d=ldst8[i]; slotc[i]=(unsigned char)off[t][d]; off[t][d]++; }
  }
  __syncthreads();
  int tot=0;
  if (t<n){
    for (int c=0;c<64;c++){ int tmp=off[c][t]; off[c][t]=(unsigned short)tot; tot+=tmp; }
  }
  sc[t] = (t<n)?tot:0;
  degv[t] = (t<n)?(unsigned short)tot:0;
  __syncthreads();
  for (int o=1;o<256;o<<=1){ int add=(t>=o)?sc[t-o]:0; __syncthreads(); sc[t]+=add; __syncthreads(); }
  if (t<n){
    int rs = sc[t]-tot;
    rstart[t]=rs;
    row_start[g*n+t]=base+rs; row_end[g*n+t]=base+rs+tot;
    // stable rank by (deg, id) ascending -> adjacent nodes have similar deg
    int d = tot, rank = 0;
    for (int j=0;j<n;j++){ int dj = degv[j]; rank += (dj<d) || (dj==d && j<t); }
    perm[g*n + rank] = g*n + t;
  }
  __syncthreads();
  if (t<64){
    int e0=t*32;
    for (int i=e0;i<e0+32;i++){
      int d=ldst8[i];
      ssrc[base + rstart[d] + off[t][d] + slotc[i]] = lsrc[i];
    }
  }
}

// ---- split-bf16 MFMA GEMM with global_load_lds staging (R11 body) ----
// XCD-aware block decode: the NH head-blocks of one row-tile are temporally
// adjacent on the SAME XCD -> X tile stays L2-hot across heads.
struct GArgs {
  const unsigned short* whi[4];
  const unsigned short* wlo[4];
  const float* bias[4];
  float*       O[4];
};

template<int NH, int BN>
__global__ __launch_bounds__(256) void k_gemm_mfma(const unsigned short* __restrict__ XHg,
                                                   const unsigned short* __restrict__ XLg,
                                                   GArgs a, float* __restrict__ psum,
                                                   float* __restrict__ psq){
  __shared__ unsigned short XH[128][32], XL[128][32], WHs[128][32], WLs[128][32];
  int bid = blockIdx.x;
  int xcd = bid & 7, j = bid >> 3;
  int head, tileOff;
  if (NH == 4){ head = j & 3; tileOff = j >> 2; }
  else        { head = 0;     tileOff = j; }
  int tilesPerXcd = (int)(gridDim.x >> 3) / NH;
  int tile = xcd * tilesPerXcd + tileOff;
  const unsigned short* WH = a.whi[head];
  const unsigned short* WL = a.wlo[head];
  size_t rowBase = (size_t)tile*128;
  int t = threadIdx.x;
  int w = t>>6, l = t&63;
  int wr = (w>>1)*64, wc = (w&1)*64;
  int lr = l&15, lk = (l>>4)*8;
  f32x4 acc[4][4] = {};
  char* bXH = (char*)&XH[0][0];
  char* bXL = (char*)&XL[0][0];
  char* bWH = (char*)&WHs[0][0];
  char* bWL = (char*)&WLs[0][0];
  for (int kc=0; kc<128; kc+=32){
    __syncthreads();
    #pragma unroll
    for (int s2=0; s2<2; s2++){
      int jj = (w*2+s2)*64 + l;          // 0..511 (16B granule index)
      int r  = jj>>2, g = jj&3;
      int gc = (g ^ ((r>>1)&3))*8;       // swizzled source col (bf16 units)
      size_t segOff = (size_t)(w*2+s2)*1024;
      size_t gx = (rowBase + r)*DD + kc + gc;
      size_t gw = (size_t)r*DD + kc + gc;
      gload_lds16(XHg + gx, bXH + segOff);
      gload_lds16(XLg + gx, bXL + segOff);
      gload_lds16(WH  + gw, bWH + segOff);
      gload_lds16(WL  + gw, bWL + segOff);
    }
    __syncthreads();
    bf16x8 ah[4], al[4], bh[4], bl[4];
    #pragma unroll
    for (int m=0;m<4;m++){
      int rr = wr + m*16 + lr;
      int bo = rr*64 + ((lk*2) ^ (((rr>>1)&3)<<4));
      ah[m] = *(const bf16x8*)(bXH + bo);
      al[m] = *(const bf16x8*)(bXL + bo);
    }
    #pragma unroll
    for (int n=0;n<4;n++){
      int rr = wc + n*16 + lr;
      int bo = rr*64 + ((lk*2) ^ (((rr>>1)&3)<<4));
      bh[n] = *(const bf16x8*)(bWH + bo);
      bl[n] = *(const bf16x8*)(bWL + bo);
    }
    #pragma unroll
    for (int m=0;m<4;m++){
      #pragma unroll
      for (int n=0;n<4;n++){
        acc[m][n] = __builtin_amdgcn_mfma_f32_16x16x32_bf16(ah[m], bh[n], acc[m][n], 0,0,0);
        acc[m][n] = __builtin_amdgcn_mfma_f32_16x16x32_bf16(ah[m], bl[n], acc[m][n], 0,0,0);
        acc[m][n] = __builtin_amdgcn_mfma_f32_16x16x32_bf16(al[m], bh[n], acc[m][n], 0,0,0);
      }
    }
  }
  float* O = a.O[head];
  const float* bias = a.bias[head];
  float cs[4] = {0.f,0.f,0.f,0.f}, cq[4] = {0.f,0.f,0.f,0.f};
  #pragma unroll
  for (int n=0;n<4;n++){
    int col = wc + n*16 + lr;
    float bv = bias[col];
    #pragma unroll
    for (int m=0;m<4;m++){
      int rb = wr + m*16 + (l>>4)*4;
      #pragma unroll
      for (int r=0;r<4;r++){
        float o = acc[m][n][r] + bv;
        if (BN) o = fmaxf(o, 0.f);
        O[(rowBase + rb + r)*DD + col] = o;
        if (BN){ cs[n] += o; cq[n] += o*o; }
      }
    }
  }
  if (BN){
    __syncthreads();
    float* redS = (float*)&XH[0][0];
    float* redQ = (float*)&XL[0][0];
    int rg = w*4 + (l>>4);
    #pragma unroll
    for (int n=0;n<4;n++){
      int col = wc + n*16 + lr;
      redS[rg*128 + col] = cs[n];
      redQ[rg*128 + col] = cq[n];
    }
    __syncthreads();
    if (t < 128){
      int c = t, w0 = (c>=64) ? 1 : 0;
      float s = 0.f, s2 = 0.f;
      #pragma unroll
      for (int dw=0; dw<2; dw++){
        int ww = w0 + dw*2;
        #pragma unroll
        for (int lq=0; lq<4; lq++){
          s  += redS[(ww*4+lq)*128 + c];
          s2 += redQ[(ww*4+lq)*128 + c];
        }
      }
      psum[tile*DD + c] = s;
      psq [tile*DD + c] = s2;
    }
  }
}

// ---- attention: 2 nodes per wave, degree-sorted pairing via perm ----
__global__ __launch_bounds__(256) void k_attn_par(
    const float* __restrict__ q, const float* __restrict__ k, const float* __restrict__ v,
    const int* __restrict__ row_start, const int* __restrict__ row_end,
    const int* __restrict__ ssrc, const int* __restrict__ perm,
    const float* __restrict__ skip,
    unsigned short* __restrict__ xh, unsigned short* __restrict__ xl)
{
  __shared__ float lg[4][2][128];
  __shared__ int   se[4][2][128];
  int nb8 = gridDim.x >> 3;
  int p = blockIdx.x;
  int lb = (p&7)*nb8 + (p>>3);          // XCD swizzle
  int w = threadIdx.x>>6, l = threadIdx.x&63;
  int h = l>>5, q32 = l&31;
  int node = perm[lb*8 + w*2 + h];      // degree-balanced pairing
  int s0 = row_start[node];
  int deg = row_end[node]-s0; if (deg>128) deg=128;
  int maxd = max(deg, __shfl_xor(deg, 32, 64));   // wave-uniform bound
  int maxd8 = (maxd+7)&~7;
  int grp = q32>>3, gl = q32&7;
  const float isd = 0.088388347648318447f;  // 1/sqrt(128)
  // prefetch edge source ids into LDS (coalesced; same-wave, no barrier needed)
  for (int e=q32; e<deg; e+=32) se[w][h][e] = ssrc[s0+e];
  if (q32==0 && deg==0) se[w][h][0] = 0;   // guard for deg==0 halves
  unsigned qoff = ((unsigned)node<<7) + (unsigned)(gl<<4);
  float4 qv0 = *(const float4*)(q + qoff);
  float4 qv1 = *(const float4*)(q + qoff + 4);
  float4 qv2 = *(const float4*)(q + qoff + 8);
  float4 qv3 = *(const float4*)(q + qoff + 12);
  for (int base=0; base<maxd; base+=4){
    int e = base + grp;
    int eok = (e<deg);
    int s = se[w][h][eok ? e : 0];
    unsigned ko = ((unsigned)s<<7) + (unsigned)(gl<<4);
    const float* kp = k + ko;
    float4 k0=*(const float4*)kp, k1=*(const float4*)(kp+4),
           k2=*(const float4*)(kp+8), k3=*(const float4*)(kp+12);
    float pd = qv0.x*k0.x+qv0.y*k0.y+qv0.z*k0.z+qv0.w*k0.w
             + qv1.x*k1.x+qv1.y*k1.y+qv1.z*k1.z+qv1.w*k1.w
             + qv2.x*k2.x+qv2.y*k2.y+qv2.z*k2.z+qv2.w*k2.w
             + qv3.x*k3.x+qv3.y*k3.y+qv3.z*k3.z+qv3.w*k3.w;
    pd += __shfl_xor(pd,1,64); pd += __shfl_xor(pd,2,64); pd += __shfl_xor(pd,4,64);
    if (gl==0 && eok) lg[w][h][e] = pd*isd;
  }
  // softmax per node-half: 32 lanes x 4 slots
  float x0v = (q32    <deg) ? lg[w][h][q32]    : -1e30f;
  float x1v = (32+q32 <deg) ? lg[w][h][32+q32] : -1e30f;
  float x2v = (64+q32 <deg) ? lg[w][h][64+q32] : -1e30f;
  float x3v = (96+q32 <deg) ? lg[w][h][96+q32] : -1e30f;
  float m = fmaxf(fmaxf(x0v,x1v), fmaxf(x2v,x3v));
  #pragma unroll
  for (int o=16;o>0;o>>=1) m = fmaxf(m, __shfl_xor(m,o,64));
  float e0 = (q32   <deg) ? __expf(x0v-m) : 0.f;
  float e1 = (32+q32<deg) ? __expf(x1v-m) : 0.f;
  float e2 = (64+q32<deg) ? __expf(x2v-m) : 0.f;
  float e3 = (96+q32<deg) ? __expf(x3v-m) : 0.f;
  float dn = (e0+e1)+(e2+e3);
  #pragma unroll
  for (int o=16;o>0;o>>=1) dn += __shfl_xor(dn,o,64);
  float rd = 1.0f/fmaxf(dn, 1e-16f);
  if (q32   <deg) lg[w][h][q32]    = e0*rd;
  if (32+q32<deg) lg[w][h][32+q32] = e1*rd;
  if (64+q32<deg) lg[w][h][64+q32] = e2*rd;
  if (96+q32<deg) lg[w][h][96+q32] = e3*rd;
  // zero-pad alpha + point padded src at row 0 (alpha 0 => exact no-op)
  for (int e=q32; e<maxd8; e+=32){
    if (e>=deg){ lg[w][h][e]=0.f; se[w][h][e]=0; }
  }
  // V-pass: chunks of 8 edges, statically unrolled -> 8 gathers in flight
  float4 a = make_float4(0.f,0.f,0.f,0.f);
  unsigned dcol = (unsigned)(q32<<2);
  for (int base=0; base<maxd8; base+=8){
    int   sv[8]; float al[8]; float4 vv[8];
    #pragma unroll
    for (int j2=0;j2<8;j2++){ sv[j2]=se[w][h][base+j2]; al[j2]=lg[w][h][base+j2]; }
    #pragma unroll
    for (int j2=0;j2<8;j2++) vv[j2] = *(const float4*)(v + (((unsigned)sv[j2]<<7) + dcol));
    #pragma unroll
    for (int j2=0;j2<8;j2++){
      a.x += al[j2]*vv[j2].x; a.y += al[j2]*vv[j2].y;
      a.z += al[j2]*vv[j2].z; a.w += al[j2]*vv[j2].w;
    }
  }
  unsigned ob = ((unsigned)node<<7) + dcol;
  float4 sk = *(const float4*)(skip + ob);
  float x0 = sk.x + a.x, x1 = sk.y + a.y, x2 = sk.z + a.z, x3 = sk.w + a.w;
  unsigned short h0=rne_bf16(x0), h1=rne_bf16(x1), h2=rne_bf16(x2), h3=rne_bf16(x3);
  unsigned short lo0=rne_bf16(x0-bf16f(h0)), lo1=rne_bf16(x1-bf16f(h1)),
                 lo2=rne_bf16(x2-bf16f(h2)), lo3=rne_bf16(x3-bf16f(h3));
  uint2 uh, ul;
  uh.x = (unsigned)h0 | ((unsigned)h1<<16); uh.y = (unsigned)h2 | ((unsigned)h3<<16);
  ul.x = (unsigned)lo0 | ((unsigned)lo1<<16); ul.y = (unsigned)lo2 | ((unsigned)lo3<<16);
  *(uint2*)(xh + ob) = uh;
  *(uint2*)(xl + ob) = ul;
}

// ---- BN final: parallel reduce of per-block partials (1 block per channel) ----
__global__ __launch_bounds__(256) void k_bnfin(const float* __restrict__ psum,
                                               const float* __restrict__ psq,
                                               float* mu, float* istd, float invN, int nblk){
  int c = blockIdx.x, t = threadIdx.x;
  __shared__ float sh[256], sh2[256];
  float s=0.f, s2=0.f;
  for (int b=t; b<nblk; b+=256){ s += psum[b*DD+c]; s2 += psq[b*DD+c]; }
  sh[t]=s; sh2[t]=s2; __syncthreads();
  for (int o=128;o>0;o>>=1){
    if (t<o){ sh[t]+=sh[t+o]; sh2[t]+=sh2[t+o]; }
    __syncthreads();
  }
  if (t==0){
    float m = sh[0]*invN;
    float var = fmaxf(sh2[0]*invN - m*m, 0.f);
    mu[c]=m; istd[c] = 1.0f/sqrtf(var + 1e-5f);
  }
}

// ---- fused per-graph: BN-score + topk + gather/scale/split + readout + compact + next CSR ----
__global__ __launch_bounds__(256) void k_pool(
    const float* __restrict__ h, const float* __restrict__ mu, const float* __restrict__ istd,
    const float* __restrict__ gma, const float* __restrict__ bta,
    const float* __restrict__ pw, const float* __restrict__ wni, int layer, int n,
    const int* __restrict__ osrc, const int* __restrict__ odst, const int* __restrict__ oecnt,
    unsigned short* __restrict__ xh, unsigned short* __restrict__ xl,
    float* __restrict__ out,
    int* __restrict__ nsrc, int* __restrict__ ndst, int* __restrict__ necnt,
    int* __restrict__ row_start, int* __restrict__ row_end, int* __restrict__ ssrc,
    int* __restrict__ perm, int do_edges)
{
  int g = blockIdx.x, t = threadIdx.x;
  int kk = n>>1;
  __shared__ float bnp[5][128];
  __shared__ float ss[256];
  __shared__ int   sel[128];
  __shared__ float skp[128];
  __shared__ int   nid[256];
  __shared__ float redm[4][128], rdsum[4][128];
  __shared__ int   esrc[ECAPG], edst[ECAPG];
  __shared__ int   sc[256];
  __shared__ unsigned short off2[64][128];   // 16KB
  __shared__ unsigned char  slot2[ECAPG];
  __shared__ int   rstart2[128];
  __shared__ unsigned short degv[128];

  if (t<128){ bnp[0][t]=mu[t]; bnp[1][t]=istd[t]; bnp[2][t]=gma[t]; bnp[3][t]=bta[t]; bnp[4][t]=pw[t]; }
  __syncthreads();
  // A: pooling scores
  if (t<n){
    const float* hr = h + ((size_t)g*n + t)*DD;
    float dot = 0.f;
    for (int c=0;c<DD;c+=4){
      float4 hv = *(const float4*)(hr+c);
      dot += ((hv.x-bnp[0][c+0])*bnp[1][c+0]*bnp[2][c+0]+bnp[3][c+0])*bnp[4][c+0];
      dot += ((hv.y-bnp[0][c+1])*bnp[1][c+1]*bnp[2][c+1]+bnp[3][c+1])*bnp[4][c+1];
      dot += ((hv.z-bnp[0][c+2])*bnp[1][c+2]*bnp[2][c+2]+bnp[3][c+2])*bnp[4][c+2];
      dot += ((hv.w-bnp[0][c+3])*bnp[1][c+3]*bnp[2][c+3]+bnp[3][c+3])*bnp[4][c+3];
    }
    ss[t] = tanhf(dot * wni[0]);
  }
  __syncthreads();
  // B: top-k exact ranking (matches jax.lax.top_k tie order)
  if (t<n){
    float si = ss[t]; int rank = 0;
    for (int j=0;j<n;j++){ float sj = ss[j]; rank += (sj>si)||((sj==si)&&(j<t)); }
    if (rank<kk){ sel[rank]=t; skp[rank]=si; nid[t]=rank; } else nid[t]=-1;
  }
  __syncthreads();
  // C: gather + BN + scale + bf16 split + readout partials
  int w = t>>6, l = t&63, d0 = l*2;
  float m0=-1e30f, m1=-1e30f, sm0=0.f, sm1=0.f;
  for (int p=w; p<kk; p+=4){
    int srow = sel[p]; float scv = skp[p];
    float2 hv = *(const float2*)(h + ((size_t)g*n + srow)*DD + d0);
    float x0 = ((hv.x-bnp[0][d0  ])*bnp[1][d0  ]*bnp[2][d0  ]+bnp[3][d0  ])*scv;
    float x1 = ((hv.y-bnp[0][d0+1])*bnp[1][d0+1]*bnp[2][d0+1]+bnp[3][d0+1])*scv;
    m0 = fmaxf(m0,x0); m1 = fmaxf(m1,x1); sm0 += x0; sm1 += x1;
    unsigned short h0=rne_bf16(x0), h1=rne_bf16(x1);
    unsigned short l0=rne_bf16(x0-bf16f(h0)), l1=rne_bf16(x1-bf16f(h1));
    size_t ob = ((size_t)g*kk + p)*DD + d0;
    *(unsigned*)(xh+ob) = (unsigned)h0 | ((unsigned)h1<<16);
    *(unsigned*)(xl+ob) = (unsigned)l0 | ((unsigned)l1<<16);
  }
  redm[w][d0]=m0; redm[w][d0+1]=m1; rdsum[w][d0]=sm0; rdsum[w][d0+1]=sm1;
  __syncthreads();
  if (t<128){
    float mx = fmaxf(fmaxf(redm[0][t],redm[1][t]), fmaxf(redm[2][t],redm[3][t]));
    float sm = rdsum[0][t]+rdsum[1][t]+rdsum[2][t]+rdsum[3][t];
    float* ob = out + (size_t)g*1152 + layer*384;
    ob[t]=mx; ob[128+t]=sm/(float)kk; ob[256+t]=sm;
  }
  if (!do_edges) return;
  // D: edge compaction (deterministic scan), local ids
  int E = oecnt ? oecnt[g] : ECAPG;
  int base = g*ECAPG;
  int cl = 0;
  for (int j=0;j<8;j++){ int i=t*8+j;
    if (i<E){ int ns=nid[osrc[base+i]-g*n], nd=nid[odst[base+i]-g*n]; if ((ns|nd)>=0) cl++; } }
  sc[t]=cl; __syncthreads();
  for (int o=1;o<256;o<<=1){ int add=(t>=o)?sc[t-o]:0; __syncthreads(); sc[t]+=add; __syncthreads(); }
  int off = sc[t]-cl;
  for (int j=0;j<8;j++){ int i=t*8+j;
    if (i<E){ int ns=nid[osrc[base+i]-g*n], nd=nid[odst[base+i]-g*n];
      if ((ns|nd)>=0){ esrc[off]=ns; edst[off]=nd; off++; } } }
  int Etot = sc[255];
  __syncthreads();
  if (t==0) necnt[g]=Etot;
  for (int i=t;i<Etot;i+=256){ nsrc[base+i]=esrc[i]+g*kk; ndst[base+i]=edst[i]+g*kk; }
  // E: next-layer CSR via chunked counting-sort (deterministic)
  for (int i=t; i<64*128/2; i+=256) ((unsigned*)off2)[i] = 0;
  __syncthreads();
  int nch = (Etot+31)>>5;
  if (t<nch){
    int e0=t*32, e1 = (e0+32<Etot)?(e0+32):Etot;
    for (int i=e0;i<e1;i++){ int d=edst[i]; slot2[i]=(unsigned char)off2[t][d]; off2[t][d]++; }
  }
  __syncthreads();
  int tot=0;
  if (t<kk){
    for (int c=0;c<nch;c++){ int tmp=off2[c][t]; off2[c][t]=(unsigned short)tot; tot+=tmp; }
  }
  sc[t] = (t<kk)?tot:0;
  degv[t&127] = (t<kk)?(unsigned short)tot:0;
  __syncthreads();
  for (int o=1;o<256;o<<=1){ int add=(t>=o)?sc[t-o]:0; __syncthreads(); sc[t]+=add; __syncthreads(); }
  if (t<kk){
    int rs = sc[t]-tot;
    rstart2[t]=rs;
    row_start[g*kk+t]=base+rs; row_end[g*kk+t]=base+rs+tot;
    // degree-sorted permutation for next-layer attention (stable by id)
    int d = tot, rank = 0;
    for (int j=0;j<kk;j++){ int dj = degv[j]; rank += (dj<d) || (dj==d && j<t); }
    perm[g*kk + rank] = g*kk + t;
  }
  __syncthreads();
  if (t<nch){
    int e0=t*32, e1 = (e0+32<Etot)?(e0+32):Etot;
    for (int i=e0;i<e1;i++){
      int d=edst[i];
      ssrc[base + rstart2[d] + off2[t][d] + slot2[i]] = esrc[i] + g*kk;  // GLOBAL id
    }
  }
}

extern "C" void kernel_launch(void* const* d_in, const int* in_sizes, int n_in,
                              void* d_out, int out_size, void* d_ws, size_t ws_size,
                              hipStream_t stream){
  const float* x0   = (const float*)d_in[0];
  const int*   eidx = (const int*)d_in[1];
  const float* Wq = (const float*)d_in[4];  const float* bq = (const float*)d_in[5];
  const float* Wk = (const float*)d_in[6];  const float* bk = (const float*)d_in[7];
  const float* Wv = (const float*)d_in[8];  const float* bv = (const float*)d_in[9];
  const float* Wsk= (const float*)d_in[10]; const float* bsk= (const float*)d_in[11];
  const float* Wt = (const float*)d_in[12]; const float* bt = (const float*)d_in[13];
  const float* gamma = (const float*)d_in[14]; const float* beta = (const float*)d_in[15];
  const float* pw = (const float*)d_in[16];

  char* w8 = (char*)d_ws;
  size_t off = 0;
  auto alloc = [&](size_t bytes)->void*{ void* p = w8+off; off += (bytes+255)&~(size_t)255; return p; };

  float* qb  = (float*)alloc((size_t)NMAX*DD*4);   // q, then transform output h
  float* kb  = (float*)alloc((size_t)NMAX*DD*4);
  float* vb  = (float*)alloc((size_t)NMAX*DD*4);
  float* xsb = (float*)alloc((size_t)NMAX*DD*4);   // skip
  unsigned short* xh = (unsigned short*)alloc((size_t)NMAX*DD*2);
  unsigned short* xl = (unsigned short*)alloc((size_t)NMAX*DD*2);
  unsigned short* whi = (unsigned short*)alloc((size_t)15*DD*DD*2);
  unsigned short* wlo = (unsigned short*)alloc((size_t)15*DD*DD*2);
  float* psum = (float*)alloc((size_t)512*DD*4);
  float* psq  = (float*)alloc((size_t)512*DD*4);
  float* mu   = (float*)alloc(DD*4);
  float* istd = (float*)alloc(DD*4);
  float* wni  = (float*)alloc(64);
  int* row_start = (int*)alloc(NMAX*4);
  int* row_end   = (int*)alloc(NMAX*4);
  int* ssrc      = (int*)alloc(ETOT*4);
  int* permb     = (int*)alloc(NMAX*4);
  int* srcA = (int*)alloc(ETOT*4);
  int* dstA = (int*)alloc(ETOT*4);
  int* srcB = (int*)alloc(ETOT*4);
  int* dstB = (int*)alloc(ETOT*4);
  int* ecntA = (int*)alloc(NGRAPH*4);
  int* ecntB = (int*)alloc(NGRAPH*4);

  k_wnorm<<<3,128,0,stream>>>(pw, wni);
  k_wprep<<<15*128,128,0,stream>>>(Wq, Wk, Wv, Wsk, Wt, whi, wlo);
  k_xsplit<<<NMAX/8,256,0,stream>>>(x0, xh, xl, NMAX*32);
  k_csr<<<NGRAPH,256,0,stream>>>(eidx, eidx+ETOT, 256, row_start, row_end, ssrc, permb);

  const int* csrc = eidx;
  const int* cdst = eidx + ETOT;
  const int* cecnt = nullptr;
  int n = 256;

  for (int layer=0; layer<3; layer++){
    int Nn = NGRAPH * n;
    int kk = n/2;

    GArgs h4;
    h4.whi[0]=whi+(size_t)(layer*5+0)*DD*DD; h4.wlo[0]=wlo+(size_t)(layer*5+0)*DD*DD; h4.bias[0]=bq +layer*DD; h4.O[0]=qb;
    h4.whi[1]=whi+(size_t)(layer*5+1)*DD*DD; h4.wlo[1]=wlo+(size_t)(layer*5+1)*DD*DD; h4.bias[1]=bk +layer*DD; h4.O[1]=kb;
    h4.whi[2]=whi+(size_t)(layer*5+2)*DD*DD; h4.wlo[2]=wlo+(size_t)(layer*5+2)*DD*DD; h4.bias[2]=bv +layer*DD; h4.O[2]=vb;
    h4.whi[3]=whi+(size_t)(layer*5+3)*DD*DD; h4.wlo[3]=wlo+(size_t)(layer*5+3)*DD*DD; h4.bias[3]=bsk+layer*DD; h4.O[3]=xsb;
    k_gemm_mfma<4,0><<<(Nn/128)*4,256,0,stream>>>(xh, xl, h4, nullptr, nullptr);

    k_attn_par<<<Nn/8,256,0,stream>>>(qb, kb, vb, row_start, row_end, ssrc, permb, xsb, xh, xl);

    GArgs h1;
    h1.whi[0]=whi+(size_t)(layer*5+4)*DD*DD; h1.wlo[0]=wlo+(size_t)(layer*5+4)*DD*DD; h1.bias[0]=bt+layer*DD; h1.O[0]=qb;
    h1.whi[1]=h1.whi[0]; h1.wlo[1]=h1.wlo[0]; h1.bias[1]=h1.bias[0]; h1.O[1]=qb;
    h1.whi[2]=h1.whi[0]; h1.wlo[2]=h1.wlo[0]; h1.bias[2]=h1.bias[0]; h1.O[2]=qb;
    h1.whi[3]=h1.whi[0]; h1.wlo[3]=h1.wlo[0]; h1.bias[3]=h1.bias[0]; h1.O[3]=qb;
    k_gemm_mfma<1,1><<<Nn/128,256,0,stream>>>(xh, xl, h1, psum, psq);

    k_bnfin<<<128,256,0,stream>>>(psum, psq, mu, istd, 1.0f/(float)Nn, Nn/128);

    int* nsrc  = (layer==0) ? srcA : srcB;
    int* ndst  = (layer==0) ? dstA : dstB;
    int* necnt = (layer==0) ? ecntA : ecntB;
    k_pool<<<NGRAPH,256,0,stream>>>(qb, mu, istd, gamma+layer*DD, beta+layer*DD,
                                    pw+layer*DD, wni+layer, layer, n,
                                    csrc, cdst, cecnt, xh, xl, (float*)d_out,
                                    nsrc, ndst, necnt, row_start, row_end, ssrc, permb,
                                    layer<2 ? 1 : 0);

    csrc = nsrc; cdst = ndst; cecnt = necnt;
    n = kk;
  }
}

// Round 16
// 304.269 us; speedup vs baseline: 1.0559x; 1.0559x over previous
//
#include <hip/hip_runtime.h>
#include <hip/hip_bf16.h>
#include <math.h>

// B=256 graphs, N=256 nodes/graph, DEG=8, D=128, L=3.
#define DD     128
#define NGRAPH 256
#define ECAPG  2048
#define ETOT   (NGRAPH*ECAPG)
#define NMAX   65536

typedef __attribute__((ext_vector_type(8))) short bf16x8;
typedef __attribute__((ext_vector_type(4))) float f32x4;

__device__ inline unsigned short rne_bf16(float x){
  union { float f; unsigned u; } c; c.f = x;
  unsigned u = c.u;
  return (unsigned short)((u + 0x7FFFu + ((u>>16)&1u)) >> 16);
}
__device__ inline float bf16f(unsigned short h){
  union { unsigned u; float f; } c; c.u = ((unsigned)h)<<16; return c.f;
}

// 16B global -> LDS direct (wave-uniform LDS base + lane*16)
__device__ inline void gload_lds16(const void* g, void* l){
  __builtin_amdgcn_global_load_lds(
      (const __attribute__((address_space(1))) unsigned*)g,
      (__attribute__((address_space(3))) unsigned*)l, 16, 0, 0);
}

// ---- pool_w inverse norms ----
__global__ __launch_bounds__(128) void k_wnorm(const float* pw, float* wni){
  int l = blockIdx.x, t = threadIdx.x;
  __shared__ float s[128];
  float v = pw[l*DD + t];
  s[t] = v*v; __syncthreads();
  for (int o=64;o>0;o>>=1){ if (t<o) s[t]+=s[t+o]; __syncthreads(); }
  if (t==0) wni[l] = 1.0f/sqrtf(s[0]);
}

// ---- weight prep: transpose + split to bf16 hi/lo; 15 matrices [128x128] ----
__global__ __launch_bounds__(128) void k_wprep(const float* Wq, const float* Wk, const float* Wv,
                                               const float* Ws, const float* Wt,
                                               unsigned short* whi, unsigned short* wlo){
  int b = blockIdx.x;            // w*128 + krow
  int w = b>>7, krow = b&127, n = threadIdx.x;
  int layer = w/5, which = w - layer*5;
  const float* W = (which==0)?Wq:(which==1)?Wk:(which==2)?Wv:(which==3)?Ws:Wt;
  float v = W[(size_t)layer*DD*DD + krow*DD + n];
  unsigned short h = rne_bf16(v);
  unsigned short l = rne_bf16(v - bf16f(h));
  whi[(size_t)w*DD*DD + (size_t)n*DD + krow] = h;   // transposed: [n][k]
  wlo[(size_t)w*DD*DD + (size_t)n*DD + krow] = l;
}

// ---- X split: fp32 -> bf16 hi/lo (initial x0 only) ----
__global__ __launch_bounds__(256) void k_xsplit(const float* __restrict__ X,
                                                unsigned short* __restrict__ xh,
                                                unsigned short* __restrict__ xl, int total4){
  int i = blockIdx.x*256 + threadIdx.x;
  if (i >= total4) return;
  float4 v = ((const float4*)X)[i];
  unsigned short h0=rne_bf16(v.x), h1=rne_bf16(v.y), h2=rne_bf16(v.z), h3=rne_bf16(v.w);
  unsigned short l0=rne_bf16(v.x-bf16f(h0)), l1=rne_bf16(v.y-bf16f(h1)),
                 l2=rne_bf16(v.z-bf16f(h2)), l3=rne_bf16(v.w-bf16f(h3));
  uint2 uh, ul;
  uh.x = (unsigned)h0 | ((unsigned)h1<<16); uh.y = (unsigned)h2 | ((unsigned)h3<<16);
  ul.x = (unsigned)l0 | ((unsigned)l1<<16); ul.y = (unsigned)l2 | ((unsigned)l3<<16);
  ((uint2*)xh)[i] = uh; ((uint2*)xl)[i] = ul;
}

// ---- CSR build (layer 0): deterministic chunked counting-sort scatter ----
__global__ __launch_bounds__(256) void k_csr(const int* __restrict__ src, const int* __restrict__ dst,
                                             int n, int* row_start, int* row_end, int* ssrc){
  int g = blockIdx.x, t = threadIdx.x;
  const int E = ECAPG;
  int base = g*ECAPG;
  __shared__ int lsrc[ECAPG];
  __shared__ unsigned char ldst8[ECAPG];
  __shared__ unsigned char slotc[ECAPG];
  __shared__ unsigned short off[64][256];   // 32KB
  __shared__ int sc[256];
  __shared__ int rstart[256];
  for (int i=t; i<64*256/2; i+=256) ((unsigned*)off)[i] = 0;
  for (int i=t; i<E; i+=256){ lsrc[i]=src[base+i]; ldst8[i]=(unsigned char)(dst[base+i]-g*n); }
  __syncthreads();
  if (t < 64){
    int e0=t*32;
    for (int i=e0;i<e0+32;i++){ int d=ldst8[i]; slotc[i]=(unsigned char)off[t][d]; off[t][d]++; }
  }
  __syncthreads();
  int tot=0;
  if (t<n){
    for (int c=0;c<64;c++){ int tmp=off[c][t]; off[c][t]=(unsigned short)tot; tot+=tmp; }
  }
  sc[t] = (t<n)?tot:0;
  __syncthreads();
  for (int o=1;o<256;o<<=1){ int add=(t>=o)?sc[t-o]:0; __syncthreads(); sc[t]+=add; __syncthreads(); }
  if (t<n){
    int rs = sc[t]-tot;
    rstart[t]=rs;
    row_start[g*n+t]=base+rs; row_end[g*n+t]=base+rs+tot;
  }
  __syncthreads();
  if (t<64){
    int e0=t*32;
    for (int i=e0;i<e0+32;i++){
      int d=ldst8[i];
      ssrc[base + rstart[d] + off[t][d] + slotc[i]] = lsrc[i];
    }
  }
}

// ---- split-bf16 MFMA GEMM with global_load_lds staging ----
// XCD-aware block decode: the NH head-blocks of one row-tile are temporally
// adjacent on the SAME XCD -> X tile stays L2-hot across heads.
struct GArgs {
  const unsigned short* whi[4];
  const unsigned short* wlo[4];
  const float* bias[4];
  float*       O[4];
};

template<int NH, int BN>
__global__ __launch_bounds__(256) void k_gemm_mfma(const unsigned short* __restrict__ XHg,
                                                   const unsigned short* __restrict__ XLg,
                                                   GArgs a, float* __restrict__ psum,
                                                   float* __restrict__ psq){
  __shared__ unsigned short XH[128][32], XL[128][32], WHs[128][32], WLs[128][32];
  int bid = blockIdx.x;
  int xcd = bid & 7, j = bid >> 3;
  int head, tileOff;
  if (NH == 4){ head = j & 3; tileOff = j >> 2; }
  else        { head = 0;     tileOff = j; }
  int tilesPerXcd = (int)(gridDim.x >> 3) / NH;
  int tile = xcd * tilesPerXcd + tileOff;
  const unsigned short* WH = a.whi[head];
  const unsigned short* WL = a.wlo[head];
  size_t rowBase = (size_t)tile*128;
  int t = threadIdx.x;
  int w = t>>6, l = t&63;
  int wr = (w>>1)*64, wc = (w&1)*64;
  int lr = l&15, lk = (l>>4)*8;
  f32x4 acc[4][4] = {};
  char* bXH = (char*)&XH[0][0];
  char* bXL = (char*)&XL[0][0];
  char* bWH = (char*)&WHs[0][0];
  char* bWL = (char*)&WLs[0][0];
  for (int kc=0; kc<128; kc+=32){
    __syncthreads();
    #pragma unroll
    for (int s2=0; s2<2; s2++){
      int jj = (w*2+s2)*64 + l;          // 0..511 (16B granule index)
      int r  = jj>>2, g = jj&3;
      int gc = (g ^ ((r>>1)&3))*8;       // swizzled source col (bf16 units)
      size_t segOff = (size_t)(w*2+s2)*1024;
      size_t gx = (rowBase + r)*DD + kc + gc;
      size_t gw = (size_t)r*DD + kc + gc;
      gload_lds16(XHg + gx, bXH + segOff);
      gload_lds16(XLg + gx, bXL + segOff);
      gload_lds16(WH  + gw, bWH + segOff);
      gload_lds16(WL  + gw, bWL + segOff);
    }
    __syncthreads();
    bf16x8 ah[4], al[4], bh[4], bl[4];
    #pragma unroll
    for (int m=0;m<4;m++){
      int rr = wr + m*16 + lr;
      int bo = rr*64 + ((lk*2) ^ (((rr>>1)&3)<<4));
      ah[m] = *(const bf16x8*)(bXH + bo);
      al[m] = *(const bf16x8*)(bXL + bo);
    }
    #pragma unroll
    for (int n=0;n<4;n++){
      int rr = wc + n*16 + lr;
      int bo = rr*64 + ((lk*2) ^ (((rr>>1)&3)<<4));
      bh[n] = *(const bf16x8*)(bWH + bo);
      bl[n] = *(const bf16x8*)(bWL + bo);
    }
    #pragma unroll
    for (int m=0;m<4;m++){
      #pragma unroll
      for (int n=0;n<4;n++){
        acc[m][n] = __builtin_amdgcn_mfma_f32_16x16x32_bf16(ah[m], bh[n], acc[m][n], 0,0,0);
        acc[m][n] = __builtin_amdgcn_mfma_f32_16x16x32_bf16(ah[m], bl[n], acc[m][n], 0,0,0);
        acc[m][n] = __builtin_amdgcn_mfma_f32_16x16x32_bf16(al[m], bh[n], acc[m][n], 0,0,0);
      }
    }
  }
  float* O = a.O[head];
  const float* bias = a.bias[head];
  float cs[4] = {0.f,0.f,0.f,0.f}, cq[4] = {0.f,0.f,0.f,0.f};
  #pragma unroll
  for (int n=0;n<4;n++){
    int col = wc + n*16 + lr;
    float bv = bias[col];
    #pragma unroll
    for (int m=0;m<4;m++){
      int rb = wr + m*16 + (l>>4)*4;
      #pragma unroll
      for (int r=0;r<4;r++){
        float o = acc[m][n][r] + bv;
        if (BN) o = fmaxf(o, 0.f);
        O[(rowBase + rb + r)*DD + col] = o;
        if (BN){ cs[n] += o; cq[n] += o*o; }
      }
    }
  }
  if (BN){
    __syncthreads();
    float* redS = (float*)&XH[0][0];
    float* redQ = (float*)&XL[0][0];
    int rg = w*4 + (l>>4);
    #pragma unroll
    for (int n=0;n<4;n++){
      int col = wc + n*16 + lr;
      redS[rg*128 + col] = cs[n];
      redQ[rg*128 + col] = cq[n];
    }
    __syncthreads();
    if (t < 128){
      int c = t, w0 = (c>=64) ? 1 : 0;
      float s = 0.f, s2 = 0.f;
      #pragma unroll
      for (int dw=0; dw<2; dw++){
        int ww = w0 + dw*2;
        #pragma unroll
        for (int lq=0; lq<4; lq++){
          s  += redS[(ww*4+lq)*128 + c];
          s2 += redQ[(ww*4+lq)*128 + c];
        }
      }
      psum[tile*DD + c] = s;
      psq [tile*DD + c] = s2;
    }
  }
}

// ---- attention: 4 nodes per wave (16 lanes / node, 8 dims / lane) ----
// K-pass keeps the exact 8-lane dot partition (bitwise-identical logits);
// softmax 16-lane x 8 slots; V-pass chunks of 4 edges x 2 float4/lane.
__global__ __launch_bounds__(256) void k_attn_par(
    const float* __restrict__ q, const float* __restrict__ k, const float* __restrict__ v,
    const int* __restrict__ row_start, const int* __restrict__ row_end,
    const int* __restrict__ ssrc, const float* __restrict__ skip,
    unsigned short* __restrict__ xh, unsigned short* __restrict__ xl)
{
  __shared__ float lg[4][4][128];
  __shared__ int   se[4][4][128];
  int nb8 = gridDim.x >> 3;
  int p = blockIdx.x;
  int lb = (p&7)*nb8 + (p>>3);          // XCD swizzle
  int w = threadIdx.x>>6, l = threadIdx.x&63;
  int h2 = l>>4, q16 = l&15;
  int node = lb*16 + w*4 + h2;
  int s0 = row_start[node];
  int deg = row_end[node]-s0; if (deg>128) deg=128;
  int mm1 = max(deg, __shfl_xor(deg,16,64));
  int maxd = max(mm1, __shfl_xor(mm1,32,64));   // wave-uniform over 4 nodes
  int maxd4 = (maxd+3)&~3;
  int grp = q16>>3, gl = q16&7;
  const float isd = 0.088388347648318447f;  // 1/sqrt(128)
  // prefetch edge source ids into LDS (same-wave, no barrier needed)
  for (int e=q16; e<deg; e+=16) se[w][h2][e] = ssrc[s0+e];
  if (q16==0 && deg==0) se[w][h2][0] = 0;   // guard for deg==0 nodes
  unsigned qoff = ((unsigned)node<<7) + (unsigned)(gl<<4);
  float4 qv0 = *(const float4*)(q + qoff);
  float4 qv1 = *(const float4*)(q + qoff + 4);
  float4 qv2 = *(const float4*)(q + qoff + 8);
  float4 qv3 = *(const float4*)(q + qoff + 12);
  for (int base=0; base<maxd; base+=2){
    int e = base + grp;
    int eok = (e<deg);
    int s = se[w][h2][eok ? e : 0];
    unsigned ko = ((unsigned)s<<7) + (unsigned)(gl<<4);
    const float* kp = k + ko;
    float4 k0=*(const float4*)kp, k1=*(const float4*)(kp+4),
           k2=*(const float4*)(kp+8), k3=*(const float4*)(kp+12);
    float pd = qv0.x*k0.x+qv0.y*k0.y+qv0.z*k0.z+qv0.w*k0.w
             + qv1.x*k1.x+qv1.y*k1.y+qv1.z*k1.z+qv1.w*k1.w
             + qv2.x*k2.x+qv2.y*k2.y+qv2.z*k2.z+qv2.w*k2.w
             + qv3.x*k3.x+qv3.y*k3.y+qv3.z*k3.z+qv3.w*k3.w;
    pd += __shfl_xor(pd,1,64); pd += __shfl_xor(pd,2,64); pd += __shfl_xor(pd,4,64);
    if (gl==0 && eok) lg[w][h2][e] = pd*isd;
  }
  // softmax per node: 16 lanes x 8 slots
  float xv[8], ex[8];
  float m = -1e30f;
  #pragma unroll
  for (int s8=0;s8<8;s8++){
    int e = s8*16+q16;
    xv[s8] = (e<deg) ? lg[w][h2][e] : -1e30f;
    m = fmaxf(m, xv[s8]);
  }
  #pragma unroll
  for (int o=8;o>0;o>>=1) m = fmaxf(m, __shfl_xor(m,o,64));
  float dn = 0.f;
  #pragma unroll
  for (int s8=0;s8<8;s8++){
    int e = s8*16+q16;
    ex[s8] = (e<deg) ? __expf(xv[s8]-m) : 0.f;
    dn += ex[s8];
  }
  #pragma unroll
  for (int o=8;o>0;o>>=1) dn += __shfl_xor(dn,o,64);
  float rd = 1.0f/fmaxf(dn, 1e-16f);
  #pragma unroll
  for (int s8=0;s8<8;s8++){
    int e = s8*16+q16;
    if (e<deg) lg[w][h2][e] = ex[s8]*rd;
  }
  // zero-pad alpha + point padded src at row 0 (alpha 0 => exact no-op)
  for (int e=q16; e<maxd4; e+=16){
    if (e>=deg){ lg[w][h2][e]=0.f; se[w][h2][e]=0; }
  }
  // V-pass: chunks of 4 edges; 16 lanes x float8 per edge row
  float4 a0 = make_float4(0.f,0.f,0.f,0.f);
  float4 a1 = make_float4(0.f,0.f,0.f,0.f);
  unsigned dcol = (unsigned)(q16<<3);
  for (int base=0; base<maxd4; base+=4){
    int sv[4]; float al[4]; float4 va[4], vb[4];
    #pragma unroll
    for (int j2=0;j2<4;j2++){ sv[j2]=se[w][h2][base+j2]; al[j2]=lg[w][h2][base+j2]; }
    #pragma unroll
    for (int j2=0;j2<4;j2++){
      const float* vp = v + (((unsigned)sv[j2]<<7) + dcol);
      va[j2] = *(const float4*)vp;
      vb[j2] = *(const float4*)(vp+4);
    }
    #pragma unroll
    for (int j2=0;j2<4;j2++){
      a0.x += al[j2]*va[j2].x; a0.y += al[j2]*va[j2].y;
      a0.z += al[j2]*va[j2].z; a0.w += al[j2]*va[j2].w;
      a1.x += al[j2]*vb[j2].x; a1.y += al[j2]*vb[j2].y;
      a1.z += al[j2]*vb[j2].z; a1.w += al[j2]*vb[j2].w;
    }
  }
  unsigned ob = ((unsigned)node<<7) + dcol;
  float4 sk0 = *(const float4*)(skip + ob);
  float4 sk1 = *(const float4*)(skip + ob + 4);
  float y0=sk0.x+a0.x, y1=sk0.y+a0.y, y2=sk0.z+a0.z, y3=sk0.w+a0.w;
  float y4=sk1.x+a1.x, y5=sk1.y+a1.y, y6=sk1.z+a1.z, y7=sk1.w+a1.w;
  unsigned short h0=rne_bf16(y0), h1=rne_bf16(y1), h2b=rne_bf16(y2), h3=rne_bf16(y3);
  unsigned short h4=rne_bf16(y4), h5=rne_bf16(y5), h6=rne_bf16(y6), h7=rne_bf16(y7);
  unsigned short l0=rne_bf16(y0-bf16f(h0)), l1=rne_bf16(y1-bf16f(h1));
  unsigned short l2=rne_bf16(y2-bf16f(h2b)), l3=rne_bf16(y3-bf16f(h3));
  unsigned short l4=rne_bf16(y4-bf16f(h4)), l5=rne_bf16(y5-bf16f(h5));
  unsigned short l6=rne_bf16(y6-bf16f(h6)), l7=rne_bf16(y7-bf16f(h7));
  uint4 uh, ul;
  uh.x = (unsigned)h0 | ((unsigned)h1<<16); uh.y = (unsigned)h2b | ((unsigned)h3<<16);
  uh.z = (unsigned)h4 | ((unsigned)h5<<16); uh.w = (unsigned)h6 | ((unsigned)h7<<16);
  ul.x = (unsigned)l0 | ((unsigned)l1<<16); ul.y = (unsigned)l2 | ((unsigned)l3<<16);
  ul.z = (unsigned)l4 | ((unsigned)l5<<16); ul.w = (unsigned)l6 | ((unsigned)l7<<16);
  *(uint4*)(xh + ob) = uh;
  *(uint4*)(xl + ob) = ul;
}

// ---- BN final: parallel reduce of per-block partials (1 block per channel) ----
__global__ __launch_bounds__(256) void k_bnfin(const float* __restrict__ psum,
                                               const float* __restrict__ psq,
                                               float* mu, float* istd, float invN, int nblk){
  int c = blockIdx.x, t = threadIdx.x;
  __shared__ float sh[256], sh2[256];
  float s=0.f, s2=0.f;
  for (int b=t; b<nblk; b+=256){ s += psum[b*DD+c]; s2 += psq[b*DD+c]; }
  sh[t]=s; sh2[t]=s2; __syncthreads();
  for (int o=128;o>0;o>>=1){
    if (t<o){ sh[t]+=sh[t+o]; sh2[t]+=sh2[t+o]; }
    __syncthreads();
  }
  if (t==0){
    float m = sh[0]*invN;
    float var = fmaxf(sh2[0]*invN - m*m, 0.f);
    mu[c]=m; istd[c] = 1.0f/sqrtf(var + 1e-5f);
  }
}

// ---- fused per-graph: BN-score + topk + gather/scale/split + readout + compact + next CSR ----
__global__ __launch_bounds__(256) void k_pool(
    const float* __restrict__ h, const float* __restrict__ mu, const float* __restrict__ istd,
    const float* __restrict__ gma, const float* __restrict__ bta,
    const float* __restrict__ pw, const float* __restrict__ wni, int layer, int n,
    const int* __restrict__ osrc, const int* __restrict__ odst, const int* __restrict__ oecnt,
    unsigned short* __restrict__ xh, unsigned short* __restrict__ xl,
    float* __restrict__ out,
    int* __restrict__ nsrc, int* __restrict__ ndst, int* __restrict__ necnt,
    int* __restrict__ row_start, int* __restrict__ row_end, int* __restrict__ ssrc, int do_edges)
{
  int g = blockIdx.x, t = threadIdx.x;
  int kk = n>>1;
  __shared__ float bnp[5][128];
  __shared__ float ss[256];
  __shared__ int   sel[128];
  __shared__ float skp[128];
  __shared__ int   nid[256];
  __shared__ float redm[4][128], rdsum[4][128];
  __shared__ int   esrc[ECAPG], edst[ECAPG];
  __shared__ int   sc[256];
  __shared__ unsigned short off2[64][128];   // 16KB
  __shared__ unsigned char  slot2[ECAPG];
  __shared__ int   rstart2[128];

  if (t<128){ bnp[0][t]=mu[t]; bnp[1][t]=istd[t]; bnp[2][t]=gma[t]; bnp[3][t]=bta[t]; bnp[4][t]=pw[t]; }
  __syncthreads();
  // A: pooling scores
  if (t<n){
    const float* hr = h + ((size_t)g*n + t)*DD;
    float dot = 0.f;
    for (int c=0;c<DD;c+=4){
      float4 hv = *(const float4*)(hr+c);
      dot += ((hv.x-bnp[0][c+0])*bnp[1][c+0]*bnp[2][c+0]+bnp[3][c+0])*bnp[4][c+0];
      dot += ((hv.y-bnp[0][c+1])*bnp[1][c+1]*bnp[2][c+1]+bnp[3][c+1])*bnp[4][c+1];
      dot += ((hv.z-bnp[0][c+2])*bnp[1][c+2]*bnp[2][c+2]+bnp[3][c+2])*bnp[4][c+2];
      dot += ((hv.w-bnp[0][c+3])*bnp[1][c+3]*bnp[2][c+3]+bnp[3][c+3])*bnp[4][c+3];
    }
    ss[t] = tanhf(dot * wni[0]);
  }
  __syncthreads();
  // B: top-k exact ranking (matches jax.lax.top_k tie order)
  if (t<n){
    float si = ss[t]; int rank = 0;
    for (int j=0;j<n;j++){ float sj = ss[j]; rank += (sj>si)||((sj==si)&&(j<t)); }
    if (rank<kk){ sel[rank]=t; skp[rank]=si; nid[t]=rank; } else nid[t]=-1;
  }
  __syncthreads();
  // C: gather + BN + scale + bf16 split + readout partials
  int w = t>>6, l = t&63, d0 = l*2;
  float m0=-1e30f, m1=-1e30f, sm0=0.f, sm1=0.f;
  for (int p=w; p<kk; p+=4){
    int srow = sel[p]; float scv = skp[p];
    float2 hv = *(const float2*)(h + ((size_t)g*n + srow)*DD + d0);
    float x0 = ((hv.x-bnp[0][d0  ])*bnp[1][d0  ]*bnp[2][d0  ]+bnp[3][d0  ])*scv;
    float x1 = ((hv.y-bnp[0][d0+1])*bnp[1][d0+1]*bnp[2][d0+1]+bnp[3][d0+1])*scv;
    m0 = fmaxf(m0,x0); m1 = fmaxf(m1,x1); sm0 += x0; sm1 += x1;
    unsigned short h0=rne_bf16(x0), h1=rne_bf16(x1);
    unsigned short l0=rne_bf16(x0-bf16f(h0)), l1=rne_bf16(x1-bf16f(h1));
    size_t ob = ((size_t)g*kk + p)*DD + d0;
    *(unsigned*)(xh+ob) = (unsigned)h0 | ((unsigned)h1<<16);
    *(unsigned*)(xl+ob) = (unsigned)l0 | ((unsigned)l1<<16);
  }
  redm[w][d0]=m0; redm[w][d0+1]=m1; rdsum[w][d0]=sm0; rdsum[w][d0+1]=sm1;
  __syncthreads();
  if (t<128){
    float mx = fmaxf(fmaxf(redm[0][t],redm[1][t]), fmaxf(redm[2][t],redm[3][t]));
    float sm = rdsum[0][t]+rdsum[1][t]+rdsum[2][t]+rdsum[3][t];
    float* ob = out + (size_t)g*1152 + layer*384;
    ob[t]=mx; ob[128+t]=sm/(float)kk; ob[256+t]=sm;
  }
  if (!do_edges) return;
  // D: edge compaction (deterministic scan), local ids
  int E = oecnt ? oecnt[g] : ECAPG;
  int base = g*ECAPG;
  int cl = 0;
  for (int j=0;j<8;j++){ int i=t*8+j;
    if (i<E){ int ns=nid[osrc[base+i]-g*n], nd=nid[odst[base+i]-g*n]; if ((ns|nd)>=0) cl++; } }
  sc[t]=cl; __syncthreads();
  for (int o=1;o<256;o<<=1){ int add=(t>=o)?sc[t-o]:0; __syncthreads(); sc[t]+=add; __syncthreads(); }
  int off = sc[t]-cl;
  for (int j=0;j<8;j++){ int i=t*8+j;
    if (i<E){ int ns=nid[osrc[base+i]-g*n], nd=nid[odst[base+i]-g*n];
      if ((ns|nd)>=0){ esrc[off]=ns; edst[off]=nd; off++; } } }
  int Etot = sc[255];
  __syncthreads();
  if (t==0) necnt[g]=Etot;
  for (int i=t;i<Etot;i+=256){ nsrc[base+i]=esrc[i]+g*kk; ndst[base+i]=edst[i]+g*kk; }
  // E: next-layer CSR via chunked counting-sort (deterministic)
  for (int i=t; i<64*128/2; i+=256) ((unsigned*)off2)[i] = 0;
  __syncthreads();
  int nch = (Etot+31)>>5;
  if (t<nch){
    int e0=t*32, e1 = (e0+32<Etot)?(e0+32):Etot;
    for (int i=e0;i<e1;i++){ int d=edst[i]; slot2[i]=(unsigned char)off2[t][d]; off2[t][d]++; }
  }
  __syncthreads();
  int tot=0;
  if (t<kk){
    for (int c=0;c<nch;c++){ int tmp=off2[c][t]; off2[c][t]=(unsigned short)tot; tot+=tmp; }
  }
  sc[t] = (t<kk)?tot:0;
  __syncthreads();
  for (int o=1;o<256;o<<=1){ int add=(t>=o)?sc[t-o]:0; __syncthreads(); sc[t]+=add; __syncthreads(); }
  if (t<kk){
    int rs = sc[t]-tot;
    rstart2[t]=rs;
    row_start[g*kk+t]=base+rs; row_end[g*kk+t]=base+rs+tot;
  }
  __syncthreads();
  if (t<nch){
    int e0=t*32, e1 = (e0+32<Etot)?(e0+32):Etot;
    for (int i=e0;i<e1;i++){
      int d=edst[i];
      ssrc[base + rstart2[d] + off2[t][d] + slot2[i]] = esrc[i] + g*kk;  // GLOBAL id
    }
  }
}

extern "C" void kernel_launch(void* const* d_in, const int* in_sizes, int n_in,
                              void* d_out, int out_size, void* d_ws, size_t ws_size,
                              hipStream_t stream){
  const float* x0   = (const float*)d_in[0];
  const int*   eidx = (const int*)d_in[1];
  const float* Wq = (const float*)d_in[4];  const float* bq = (const float*)d_in[5];
  const float* Wk = (const float*)d_in[6];  const float* bk = (const float*)d_in[7];
  const float* Wv = (const float*)d_in[8];  const float* bv = (const float*)d_in[9];
  const float* Wsk= (const float*)d_in[10]; const float* bsk= (const float*)d_in[11];
  const float* Wt = (const float*)d_in[12]; const float* bt = (const float*)d_in[13];
  const float* gamma = (const float*)d_in[14]; const float* beta = (const float*)d_in[15];
  const float* pw = (const float*)d_in[16];

  char* w8 = (char*)d_ws;
  size_t off = 0;
  auto alloc = [&](size_t bytes)->void*{ void* p = w8+off; off += (bytes+255)&~(size_t)255; return p; };

  float* qb  = (float*)alloc((size_t)NMAX*DD*4);   // q, then transform output h
  float* kb  = (float*)alloc((size_t)NMAX*DD*4);
  float* vb  = (float*)alloc((size_t)NMAX*DD*4);
  float* xsb = (float*)alloc((size_t)NMAX*DD*4);   // skip
  unsigned short* xh = (unsigned short*)alloc((size_t)NMAX*DD*2);
  unsigned short* xl = (unsigned short*)alloc((size_t)NMAX*DD*2);
  unsigned short* whi = (unsigned short*)alloc((size_t)15*DD*DD*2);
  unsigned short* wlo = (unsigned short*)alloc((size_t)15*DD*DD*2);
  float* psum = (float*)alloc((size_t)512*DD*4);
  float* psq  = (float*)alloc((size_t)512*DD*4);
  float* mu   = (float*)alloc(DD*4);
  float* istd = (float*)alloc(DD*4);
  float* wni  = (float*)alloc(64);
  int* row_start = (int*)alloc(NMAX*4);
  int* row_end   = (int*)alloc(NMAX*4);
  int* ssrc      = (int*)alloc(ETOT*4);
  int* srcA = (int*)alloc(ETOT*4);
  int* dstA = (int*)alloc(ETOT*4);
  int* srcB = (int*)alloc(ETOT*4);
  int* dstB = (int*)alloc(ETOT*4);
  int* ecntA = (int*)alloc(NGRAPH*4);
  int* ecntB = (int*)alloc(NGRAPH*4);

  k_wnorm<<<3,128,0,stream>>>(pw, wni);
  k_wprep<<<15*128,128,0,stream>>>(Wq, Wk, Wv, Wsk, Wt, whi, wlo);
  k_xsplit<<<NMAX/8,256,0,stream>>>(x0, xh, xl, NMAX*32);
  k_csr<<<NGRAPH,256,0,stream>>>(eidx, eidx+ETOT, 256, row_start, row_end, ssrc);

  const int* csrc = eidx;
  const int* cdst = eidx + ETOT;
  const int* cecnt = nullptr;
  int n = 256;

  for (int layer=0; layer<3; layer++){
    int Nn = NGRAPH * n;
    int kk = n/2;

    GArgs h4;
    h4.whi[0]=whi+(size_t)(layer*5+0)*DD*DD; h4.wlo[0]=wlo+(size_t)(layer*5+0)*DD*DD; h4.bias[0]=bq +layer*DD; h4.O[0]=qb;
    h4.whi[1]=whi+(size_t)(layer*5+1)*DD*DD; h4.wlo[1]=wlo+(size_t)(layer*5+1)*DD*DD; h4.bias[1]=bk +layer*DD; h4.O[1]=kb;
    h4.whi[2]=whi+(size_t)(layer*5+2)*DD*DD; h4.wlo[2]=wlo+(size_t)(layer*5+2)*DD*DD; h4.bias[2]=bv +layer*DD; h4.O[2]=vb;
    h4.whi[3]=whi+(size_t)(layer*5+3)*DD*DD; h4.wlo[3]=wlo+(size_t)(layer*5+3)*DD*DD; h4.bias[3]=bsk+layer*DD; h4.O[3]=xsb;
    k_gemm_mfma<4,0><<<(Nn/128)*4,256,0,stream>>>(xh, xl, h4, nullptr, nullptr);

    k_attn_par<<<Nn/16,256,0,stream>>>(qb, kb, vb, row_start, row_end, ssrc, xsb, xh, xl);

    GArgs h1;
    h1.whi[0]=whi+(size_t)(layer*5+4)*DD*DD; h1.wlo[0]=wlo+(size_t)(layer*5+4)*DD*DD; h1.bias[0]=bt+layer*DD; h1.O[0]=qb;
    h1.whi[1]=h1.whi[0]; h1.wlo[1]=h1.wlo[0]; h1.bias[1]=h1.bias[0]; h1.O[1]=qb;
    h1.whi[2]=h1.whi[0]; h1.wlo[2]=h1.wlo[0]; h1.bias[2]=h1.bias[0]; h1.O[2]=qb;
    h1.whi[3]=h1.whi[0]; h1.wlo[3]=h1.wlo[0]; h1.bias[3]=h1.bias[0]; h1.O[3]=qb;
    k_gemm_mfma<1,1><<<Nn/128,256,0,stream>>>(xh, xl, h1, psum, psq);

    k_bnfin<<<128,256,0,stream>>>(psum, psq, mu, istd, 1.0f/(float)Nn, Nn/128);

    int* nsrc  = (layer==0) ? srcA : srcB;
    int* ndst  = (layer==0) ? dstA : dstB;
    int* necnt = (layer==0) ? ecntA : ecntB;
    k_pool<<<NGRAPH,256,0,stream>>>(qb, mu, istd, gamma+layer*DD, beta+layer*DD,
                                    pw+layer*DD, wni+layer, layer, n,
                                    csrc, cdst, cecnt, xh, xl, (float*)d_out,
                                    nsrc, ndst, necnt, row_start, row_end, ssrc, layer<2 ? 1 : 0);

    csrc = nsrc; cdst = ndst; cecnt = necnt;
    n = kk;
  }
}